// Round 11
// baseline (187.614 us; speedup 1.0000x reference)
//
#include <hip/hip_runtime.h>
#include <hip/hip_bf16.h>
#include <math.h>

#define En   8
#define Bn   4096
#define Ln   512
#define K1n  1024   // 2L
#define H1n  1024
#define H2n  512
#define Cn   40
#define NP3  48     // layer-3 padded N
#define NTR  72     // max row tiles at TM=64 (4096/64 + 8)

typedef unsigned short u16;
typedef __attribute__((ext_vector_type(8))) short bf16x8;
typedef __attribute__((ext_vector_type(4))) float f32x4;

// f32 -> bf16 (RNE)
__device__ __forceinline__ u16 f2b(float f) {
    union { float f; unsigned int u; } v; v.f = f;
    unsigned int r = v.u + 0x7FFF + ((v.u >> 16) & 1);
    return (u16)(r >> 16);
}
// pack two f32 -> (bf16(b)<<16)|bf16(a)
__device__ __forceinline__ unsigned int f2b2(float a, float b) {
    union { float f; unsigned int u; } x, y; x.f = a; y.f = b;
    unsigned int ra = (x.u + 0x7FFF + ((x.u >> 16) & 1)) >> 16;
    unsigned int rb = (y.u + 0x7FFF + ((y.u >> 16) & 1)) & 0xFFFF0000u;
    return rb | ra;
}

// async global->LDS 16B copy; LDS dest = wave-uniform base + lane*16.
__device__ __forceinline__ void g2l16(const void* g, void* l) {
    __builtin_amdgcn_global_load_lds(
        (const __attribute__((address_space(1))) unsigned int*)(unsigned long long)g,
        (__attribute__((address_space(3))) unsigned int*)(unsigned int)(unsigned long long)l,
        16, 0, 0);
}

// 64x64 f32->bf16 transpose tile via LDS (needs 64*65 floats = 16.6 KB)
__device__ __forceinline__ void wtrans64(
    const float* __restrict__ Wsrc, u16* __restrict__ Wdst,
    int K, int N, int k0, int n0, int tid, float* sm)
{
    #pragma unroll
    for (int s = 0; s < 4; s++) {
        int idx = tid + s * 256;
        int kk = idx >> 4, c4 = (idx & 15) * 4;
        float4 v = *(const float4*)&Wsrc[(size_t)(k0 + kk) * N + n0 + c4];
        float* row = sm + kk * 65 + c4;
        row[0] = v.x; row[1] = v.y; row[2] = v.z; row[3] = v.w;
    }
    __syncthreads();
    #pragma unroll
    for (int s = 0; s < 4; s++) {
        int idx = tid + s * 256;
        int nn = idx >> 4, kc = (idx & 15) * 4;
        ushort4 o = make_ushort4(f2b(sm[(kc + 0) * 65 + nn]), f2b(sm[(kc + 1) * 65 + nn]),
                                 f2b(sm[(kc + 2) * 65 + nn]), f2b(sm[(kc + 3) * 65 + nn]));
        *(ushort4*)&Wdst[(size_t)(n0 + nn) * K + k0 + kc] = o;
    }
}

// ---------------------------------------------------------------------------
// route: single block -> meta[0..8], perm[4096]
// ---------------------------------------------------------------------------
__global__ __launch_bounds__(256) void route_kernel(
    const int* __restrict__ label, int* __restrict__ meta, int* __restrict__ perm)
{
    __shared__ int cnt[En], off[En + 1];
    const int tid = threadIdx.x;
    if (tid < En) cnt[tid] = 0;
    __syncthreads();
    for (int b = tid; b < Bn; b += 256) atomicAdd(&cnt[label[b]], 1);
    __syncthreads();
    if (tid == 0) {
        int run = 0;
        for (int e = 0; e < En; e++) { off[e] = run; run += cnt[e]; }
        off[En] = run;
    }
    __syncthreads();
    if (tid < En) cnt[tid] = off[tid];
    __syncthreads();
    for (int b = tid; b < Bn; b += 256) {
        int e = label[b];
        perm[atomicAdd(&cnt[e], 1)] = b;
    }
    if (tid <= En) meta[tid] = off[tid];
}

// ---------------------------------------------------------------------------
// L1: grouped GEMM + ELU -> h1b bf16, staging BOTH operands directly from
// native f32 (A: gather x via perm; B: W1 [k][n] register micro-transpose).
// 64x64 tile, BK=64, double-buffered, software-pipelined.
// Swizzles: A phys-chunk = logical ^ (row&7); B sigma(n) = (n ^ (n>>3)) & 7
// (conflict-free for the 4-col b64 write pattern AND the b128 frag read).
// Tail blocks (>= 1152): W2t transpose / W3t transpose+pad / out bias-init.
// ---------------------------------------------------------------------------
__global__ __launch_bounds__(256) void gemm1_kernel(
    const float* __restrict__ xp, const float* __restrict__ xs,
    const float* __restrict__ W1, const float* __restrict__ b1,
    const int* __restrict__ meta, const int* __restrict__ perm,
    u16* __restrict__ h1b,
    const float* __restrict__ W2f, const float* __restrict__ W3f,
    const float* __restrict__ b3v, const int* __restrict__ labelv,
    u16* __restrict__ W2t_o, u16* __restrict__ W3t_o, float* __restrict__ outf)
{
    constexpr int TM = 64, BK = 64, T = K1n / BK, NTC = H1n / 64;
    __shared__ __align__(16) u16 SM[16384];   // 2 stages x (A 8KB + B 8KB) = 32 KB

    const int tid = threadIdx.x;
    const int bx = blockIdx.x;

    if (bx >= NTR * NTC) {
        int jb = bx - NTR * NTC;
        if (jb < 1024) {               // W2 -> W2t [e][n][k] bf16
            int e = jb >> 7, rem = jb & 127;
            int k0 = (rem >> 3) * 64, n0 = (rem & 7) * 64;
            wtrans64(W2f + (size_t)e * H1n * H2n, W2t_o + (size_t)e * H2n * H1n,
                     H1n, H2n, k0, n0, tid, (float*)SM);
        } else if (jb < 1024 + 128) {  // W3 -> W3t [e][48][512] bf16, pad 0
            int b = jb - 1024;
            int e = b >> 4, k0 = (b & 15) * 32;
            const float* src = W3f + (size_t)e * H2n * Cn;
            u16* dst = W3t_o + (size_t)e * NP3 * H2n;
            float* t = (float*)SM;     // [32][41]
            #pragma unroll
            for (int s = 0; s < 5; s++) {
                int idx = tid + s * 256;
                int kk = idx / Cn, nn = idx - kk * Cn;
                if (kk < 32) t[kk * 41 + nn] = src[(size_t)(k0 + kk) * Cn + nn];
            }
            __syncthreads();
            #pragma unroll
            for (int s = 0; s < 6; s++) {
                int idx = tid + s * 256;
                int nn = idx >> 5, kk = idx & 31;
                float v = (nn < Cn) ? t[kk * 41 + nn] : 0.f;
                dst[(size_t)nn * H2n + k0 + kk] = f2b(v);
            }
        } else {                       // out[r][c] = b3[label[r]][c]
            int b = jb - (1024 + 128);
            int r0 = b * 64;
            #pragma unroll
            for (int s = 0; s < 10; s++) {
                int idx = tid + s * 256;
                int r = r0 + idx / Cn;
                int c = idx - (idx / Cn) * Cn;
                outf[(size_t)r * Cn + c] = b3v[labelv[r] * Cn + c];
            }
        }
        return;
    }

    const int rt = bx % NTR;
    const int col0 = (bx / NTR) * 64;

    int expert = -1, row0 = 0, rowmax = 0, acc_t = 0;
    int prev = meta[0];
    #pragma unroll
    for (int e = 0; e < En; e++) {
        int nxt = meta[e + 1];
        int c = nxt - prev;
        int t = (c + TM - 1) / TM;
        if (expert < 0 && rt < acc_t + t) {
            expert = e; row0 = prev + (rt - acc_t) * TM; rowmax = nxt - 1;
        }
        acc_t += t; prev = nxt;
    }
    if (expert < 0) return;

    const int lane = tid & 63;
    const int wid = tid >> 6;
    const int wm = (wid & 1) * 32;
    const int wn = (wid >> 1) * 32;
    const int l15 = lane & 15;
    const int lq = lane >> 4;

    // --- A staging geometry (sync f32 gather): row rl, 2 logical chunks ---
    const int rl = tid >> 2, lk2 = (tid & 3) * 2;
    int rg = row0 + rl; if (rg > rowmax) rg = rowmax;
    rg = perm[rg];
    const float* axp = xp + (size_t)rg * Ln + lk2 * 8;
    const float* axs = xs + (size_t)rg * Ln + lk2 * 8;
    const int aslot0 = rl * 64 + (((lk2    ) ^ (rl & 7)) << 3);
    const int aslot1 = rl * 64 + (((lk2 + 1) ^ (rl & 7)) << 3);

    // --- B staging geometry (sync f32 micro-transpose): 4k x 4n per thread ---
    const int kg = tid >> 4;            // 0..15 -> k rows kg*4..+3
    const int n4 = (tid & 15) * 4;      // 4 consecutive tile-local cols
    const float* bbase = W1 + (size_t)expert * K1n * H1n + (size_t)(kg * 4) * H1n + col0 + n4;
    int bslot[4];
    #pragma unroll
    for (int i = 0; i < 4; i++) {
        int nl = n4 + i;
        int sig = (nl ^ (nl >> 3)) & 7;
        bslot[i] = 4096 + nl * 64 + ((((kg >> 1) ^ sig) << 3) + (kg & 1) * 4);
    }

    // frag-read swizzle terms
    const int csw = l15 & 7;
    int sB[2];
    #pragma unroll
    for (int j = 0; j < 2; j++) {
        int nl = wn + j * 16 + l15;
        sB[j] = (nl ^ (nl >> 3)) & 7;
    }

    f32x4 acc[2][2];
    #pragma unroll
    for (int i = 0; i < 2; i++)
        #pragma unroll
        for (int j = 0; j < 2; j++) acc[i][j] = (f32x4){0.f, 0.f, 0.f, 0.f};

    // prologue: stage tile 0 into stage 0
    {
        const float* ap = axp;      // t=0 -> xp half
        float4 av0 = *(const float4*)(ap + 0),  av1 = *(const float4*)(ap + 4);
        float4 av2 = *(const float4*)(ap + 8),  av3 = *(const float4*)(ap + 12);
        float4 wv[4];
        #pragma unroll
        for (int d = 0; d < 4; d++) wv[d] = *(const float4*)(bbase + (size_t)d * H1n);
        *(uint4*)&SM[aslot0] = make_uint4(f2b2(av0.x, av0.y), f2b2(av0.z, av0.w),
                                          f2b2(av1.x, av1.y), f2b2(av1.z, av1.w));
        *(uint4*)&SM[aslot1] = make_uint4(f2b2(av2.x, av2.y), f2b2(av2.z, av2.w),
                                          f2b2(av3.x, av3.y), f2b2(av3.z, av3.w));
        #pragma unroll
        for (int i = 0; i < 4; i++) {
            float c0 = ((const float*)&wv[0])[i], c1 = ((const float*)&wv[1])[i];
            float c2 = ((const float*)&wv[2])[i], c3 = ((const float*)&wv[3])[i];
            *(uint2*)&SM[bslot[i]] = make_uint2(f2b2(c0, c1), f2b2(c2, c3));
        }
    }

    for (int t = 0; t < T; t++) {
        __syncthreads();
        const u16* As = &SM[(t & 1) * 8192];
        const u16* Bs = As + 4096;
        u16* Sn = &SM[((t + 1) & 1) * 8192];

        float4 av0, av1, av2, av3, wv[4];
        const bool pf = (t + 1 < T);
        if (pf) {
            const int tn = t + 1;
            const float* ap = (tn < 8) ? (axp + tn * 64) : (axs + (tn - 8) * 64);
            av0 = *(const float4*)(ap + 0);  av1 = *(const float4*)(ap + 4);
            av2 = *(const float4*)(ap + 8);  av3 = *(const float4*)(ap + 12);
            const float* bp = bbase + (size_t)tn * 64 * H1n;
            #pragma unroll
            for (int d = 0; d < 4; d++) wv[d] = *(const float4*)(bp + (size_t)d * H1n);
        }

        #pragma unroll
        for (int h = 0; h < 2; h++) {
            const int ksA = ((h * 4 + lq) ^ csw) << 3;
            bf16x8 af[2], bf[2];
            #pragma unroll
            for (int i = 0; i < 2; i++)
                af[i] = *(const bf16x8*)&As[(wm + i * 16 + l15) * 64 + ksA];
            #pragma unroll
            for (int j = 0; j < 2; j++)
                bf[j] = *(const bf16x8*)&Bs[(wn + j * 16 + l15) * 64 +
                                            (((h * 4 + lq) ^ sB[j]) << 3)];
            #pragma unroll
            for (int i = 0; i < 2; i++)
                #pragma unroll
                for (int j = 0; j < 2; j++)
                    acc[i][j] = __builtin_amdgcn_mfma_f32_16x16x32_bf16(
                        af[i], bf[j], acc[i][j], 0, 0, 0);
        }

        if (pf) {
            *(uint4*)&Sn[aslot0] = make_uint4(f2b2(av0.x, av0.y), f2b2(av0.z, av0.w),
                                              f2b2(av1.x, av1.y), f2b2(av1.z, av1.w));
            *(uint4*)&Sn[aslot1] = make_uint4(f2b2(av2.x, av2.y), f2b2(av2.z, av2.w),
                                              f2b2(av3.x, av3.y), f2b2(av3.z, av3.w));
            #pragma unroll
            for (int i = 0; i < 4; i++) {
                float c0 = ((const float*)&wv[0])[i], c1 = ((const float*)&wv[1])[i];
                float c2 = ((const float*)&wv[2])[i], c3 = ((const float*)&wv[3])[i];
                *(uint2*)&Sn[bslot[i]] = make_uint2(f2b2(c0, c1), f2b2(c2, c3));
            }
        }
    }

    // epilogue: bias + ELU -> h1b bf16.  C/D: col=l15, row=lq*4+reg
    #pragma unroll
    for (int i = 0; i < 2; i++) {
        #pragma unroll
        for (int j = 0; j < 2; j++) {
            int col = col0 + wn + j * 16 + l15;
            float bv = b1[expert * H1n + col];
            #pragma unroll
            for (int r = 0; r < 4; r++) {
                int grow = row0 + wm + i * 16 + lq * 4 + r;
                if (grow <= rowmax) {
                    float v = acc[i][j][r] + bv;
                    v = (v > 0.f) ? v : (expf(v) - 1.f);
                    h1b[(size_t)grow * H1n + col] = f2b(v);
                }
            }
        }
    }
}

// ---------------------------------------------------------------------------
// L2 + fused L3 (R10 structure): A async DMA from h1b, B async DMA from W2t,
// layer-3 k-split epilogue with atomicAdd into out (pre-init'd with b3).
// ---------------------------------------------------------------------------
__global__ __launch_bounds__(256) void gemm2_kernel(
    const u16* __restrict__ A, const u16* __restrict__ Wt,
    const float* __restrict__ bias, const int* __restrict__ meta,
    const int* __restrict__ perm, const u16* __restrict__ Wt3,
    float* __restrict__ outf)
{
    constexpr int TM = 64, BK = 64, K = H1n, N = H2n, T = K / BK;
    __shared__ __align__(16) u16 SM[16384];

    const int tid = threadIdx.x;
    const int bx = blockIdx.x;

    const int rt = bx % NTR;
    const int col0 = (bx / NTR) * 64;

    int expert = -1, row0 = 0, rowmax = 0, acc_t = 0;
    int prev = meta[0];
    #pragma unroll
    for (int e = 0; e < En; e++) {
        int nxt = meta[e + 1];
        int c = nxt - prev;
        int t = (c + TM - 1) / TM;
        if (expert < 0 && rt < acc_t + t) {
            expert = e; row0 = prev + (rt - acc_t) * TM; rowmax = nxt - 1;
        }
        acc_t += t; prev = nxt;
    }
    if (expert < 0) return;

    const u16* Wexp = Wt + (size_t)expert * N * K;

    const int lane = tid & 63;
    const int wid = tid >> 6;
    const int wm = (wid & 1) * 32;
    const int wn = (wid >> 1) * 32;
    const int l15 = lane & 15;
    const int lq = lane >> 4;

    const u16* aptr[2]; const u16* bptr[2];
    int aoff[2], boff[2];
    #pragma unroll
    for (int s = 0; s < 2; s++) {
        int idx = tid + s * 256;
        int rl = idx >> 3, c = idx & 7;
        int kq = c ^ (rl & 7);
        int rg = row0 + rl; if (rg > rowmax) rg = rowmax;
        aptr[s] = A + (size_t)rg * K + kq * 8;
        bptr[s] = Wexp + (size_t)(col0 + rl) * K + kq * 8;
        aoff[s] = idx * 8;
        boff[s] = 4096 + idx * 8;
    }
    const int csw = l15 & 7;

    f32x4 acc[2][2];
    #pragma unroll
    for (int i = 0; i < 2; i++)
        #pragma unroll
        for (int j = 0; j < 2; j++) acc[i][j] = (f32x4){0.f, 0.f, 0.f, 0.f};

    #pragma unroll
    for (int s = 0; s < 2; s++) {
        g2l16(aptr[s], &SM[aoff[s]]);
        g2l16(bptr[s], &SM[boff[s]]);
    }

    for (int t = 0; t < T; t++) {
        __syncthreads();
        const u16* As = &SM[(t & 1) * 8192];
        const u16* Bs = As + 4096;
        if (t + 1 < T) {
            int base = ((t + 1) & 1) * 8192;
            int ko = (t + 1) * BK;
            #pragma unroll
            for (int s = 0; s < 2; s++) {
                g2l16(aptr[s] + ko, &SM[base + aoff[s]]);
                g2l16(bptr[s] + ko, &SM[base + boff[s]]);
            }
        }
        #pragma unroll
        for (int h = 0; h < 2; h++) {
            const int ksw = ((h * 4 + lq) ^ csw) << 3;
            bf16x8 af[2], bf[2];
            #pragma unroll
            for (int i = 0; i < 2; i++)
                af[i] = *(const bf16x8*)&As[(wm + i * 16 + l15) * BK + ksw];
            #pragma unroll
            for (int j = 0; j < 2; j++)
                bf[j] = *(const bf16x8*)&Bs[(wn + j * 16 + l15) * BK + ksw];
            #pragma unroll
            for (int i = 0; i < 2; i++)
                #pragma unroll
                for (int j = 0; j < 2; j++)
                    acc[i][j] = __builtin_amdgcn_mfma_f32_16x16x32_bf16(
                        af[i], bf[j], acc[i][j], 0, 0, 0);
        }
    }

    // fused layer 3: ELU h-tile -> LDS -> MFMA vs Wt3 -> atomicAdd
    __syncthreads();
    u16* H = &SM[0];   // [64][72] bf16
    #pragma unroll
    for (int i = 0; i < 2; i++) {
        #pragma unroll
        for (int j = 0; j < 2; j++) {
            int col = wn + j * 16 + l15;
            float bv = bias[expert * N + col0 + col];
            #pragma unroll
            for (int r = 0; r < 4; r++) {
                float v = acc[i][j][r] + bv;
                v = (v > 0.f) ? v : (expf(v) - 1.f);
                H[(wm + i * 16 + lq * 4 + r) * 72 + col] = f2b(v);
            }
        }
    }
    __syncthreads();
    const int rh = wid * 16;
    f32x4 a3[3];
    #pragma unroll
    for (int j = 0; j < 3; j++) a3[j] = (f32x4){0.f, 0.f, 0.f, 0.f};
    #pragma unroll
    for (int ki = 0; ki < 2; ki++) {
        bf16x8 ha = *(const bf16x8*)&H[(rh + l15) * 72 + ki * 32 + lq * 8];
        #pragma unroll
        for (int j = 0; j < 3; j++) {
            bf16x8 wb = *(const bf16x8*)
                &Wt3[((size_t)expert * NP3 + j * 16 + l15) * H2n + col0 + ki * 32 + lq * 8];
            a3[j] = __builtin_amdgcn_mfma_f32_16x16x32_bf16(ha, wb, a3[j], 0, 0, 0);
        }
    }
    #pragma unroll
    for (int j = 0; j < 3; j++) {
        int col = j * 16 + l15;
        if (col < Cn) {
            #pragma unroll
            for (int r = 0; r < 4; r++) {
                int grow = row0 + rh + lq * 4 + r;
                if (grow <= rowmax)
                    atomicAdd(&outf[(size_t)perm[grow] * Cn + col], a3[j][r]);
            }
        }
    }
}

// ---------------------------------------------------------------------------
extern "C" void kernel_launch(void* const* d_in, const int* in_sizes, int n_in,
                              void* d_out, int out_size, void* d_ws, size_t ws_size,
                              hipStream_t stream)
{
    const float* xs = (const float*)d_in[0];
    const float* xp = (const float*)d_in[1];
    const float* W1 = (const float*)d_in[2];
    const float* b1 = (const float*)d_in[3];
    const float* W2 = (const float*)d_in[4];
    const float* b2 = (const float*)d_in[5];
    const float* W3 = (const float*)d_in[6];
    const float* b3 = (const float*)d_in[7];
    const int* label = (const int*)d_in[8];
    float* out = (float*)d_out;

    char* ws = (char*)d_ws;
    int* meta = (int*)ws;                                    // 64 B
    int* perm = (int*)(ws + 64);                             // 16 KB
    u16* h1b = (u16*)(ws + (64 << 10));                      // 8 MB [4096][1024] sorted
    u16* W2t = (u16*)(ws + (64 << 10) + (8 << 20));          // 8 MB [8][512][1024]
    u16* W3t = (u16*)(ws + (64 << 10) + (16 << 20));         // 393 KB [8][48][512]

    route_kernel<<<1, 256, 0, stream>>>(label, meta, perm);

    // L1 GEMM (1152 blocks) + tail jobs (1216 blocks: W2t/W3t/out-init)
    gemm1_kernel<<<NTR * 16 + 1216, 256, 0, stream>>>(
        xp, xs, W1, b1, meta, perm, h1b, W2, W3, b3, label, W2t, W3t, out);

    // L2 + fused L3 (576 blocks)
    gemm2_kernel<<<NTR * 8, 256, 0, stream>>>(
        h1b, W2t, b2, meta, perm, W3t, out);
}